// Round 15
// baseline (307.158 us; speedup 1.0000x reference)
//
#include <hip/hip_runtime.h>
#include <hip/hip_bf16.h>

typedef _Float16 half8 __attribute__((ext_vector_type(8)));
typedef _Float16 half4 __attribute__((ext_vector_type(4)));
typedef float floatx4 __attribute__((ext_vector_type(4)));

#define EMBED 1024
#define SEQ   2048
#define BATCH 32
#define M_TOT (BATCH * SEQ)   // 65536 rows
#define KDIM  1024
#define NDIM  1024

// async global->LDS, 16B per lane, dest = wave-uniform base + lane*16
#define GLOAD16(g, l) __builtin_amdgcn_global_load_lds(                      \
    (const __attribute__((address_space(1))) void*)(g),                      \
    (__attribute__((address_space(3))) void*)(l), 16, 0, 0)

// ---------------------------------------------------------------------------
// Kernel 1: transpose + convert W[K][N] fp32 -> Wt[N][K] fp16 (both paths)
// ---------------------------------------------------------------------------
__global__ void transpose_w_kernel(const float* __restrict__ W,
                                   _Float16* __restrict__ Wt) {
    __shared__ float t[32][33];
    const int kt = blockIdx.x * 32;
    const int nt = blockIdx.y * 32;
    #pragma unroll
    for (int i = 0; i < 4; ++i)
        t[threadIdx.y + 8 * i][threadIdx.x] =
            W[(size_t)(kt + threadIdx.y + 8 * i) * NDIM + nt + threadIdx.x];
    __syncthreads();
    #pragma unroll
    for (int i = 0; i < 4; ++i)
        Wt[(size_t)(nt + threadIdx.y + 8 * i) * KDIM + kt + threadIdx.x] =
            (_Float16)t[threadIdx.x][threadIdx.y + 8 * i];
}

// ---------------------------------------------------------------------------
// Kernel 2: zero scores + out
// ---------------------------------------------------------------------------
__global__ void zero_kernel(float* __restrict__ scores, float* __restrict__ out) {
    const int i = blockIdx.x * 256 + threadIdx.x;
    if (i < M_TOT) scores[i] = 0.0f;
    if (i < BATCH * EMBED) out[i] = 0.0f;
}

// ---------------------------------------------------------------------------
// Kernel 2b: convert x fp32 -> fp16 (64M elements)
// ---------------------------------------------------------------------------
__global__ __launch_bounds__(256) void cvt_x_kernel(const float* __restrict__ x,
                                                    _Float16* __restrict__ x16) {
    const size_t stride = (size_t)gridDim.x * 256 * 8;
    for (size_t i = ((size_t)blockIdx.x * 256 + threadIdx.x) * 8;
         i < (size_t)M_TOT * KDIM; i += stride) {
        const float4 a = *(const float4*)(x + i);
        const float4 b = *(const float4*)(x + i + 4);
        half8 h;
        h[0] = (_Float16)a.x; h[1] = (_Float16)a.y; h[2] = (_Float16)a.z; h[3] = (_Float16)a.w;
        h[4] = (_Float16)b.x; h[5] = (_Float16)b.y; h[6] = (_Float16)b.z; h[7] = (_Float16)b.w;
        *(half8*)(x16 + i) = h;
    }
}

// ---------------------------------------------------------------------------
// Kernel 3: fused scores GEMM — 8-PHASE 256x256 TEMPLATE (T3+T4), faithful.
// BM=BN=256, BK=64, 512 threads = 8 waves (2M x 4N), wave output 128x64,
// acc[8][4] 16x16 frags, 64 MFMA / K-tile / wave.
// LDS: As/Bs [2 dbuf][2 half][128 rows][64 halves] = 128 KiB total.
// Tile t lives in buf[t&1].  Group(t) = 4 phases computing tile t; it stages
// tile t+1 (4 half-tiles, one per phase, 2 gload_lds/wave each) into
// buf[(t+1)&1] — never the buffer being read.  Loads stay in flight across
// the group (counted vmcnt(2) ONCE per group at ph0, never 0 until the
// final drain group).  Raw s_barrier (no implicit vmcnt drain), 2/phase.
// Swizzle for 128B rows: phys 16B-slot p = s ^ (row&7); staged via
// pre-swizzled GLOBAL slot g = (l&7)^(l>>3), LDS dest linear (rule 21).
// ---------------------------------------------------------------------------
__global__ __launch_bounds__(512, 2) void score_gemm13(
    const _Float16* __restrict__ x16, const _Float16* __restrict__ Wt,
    const float* __restrict__ bias, const float* __restrict__ ctx,
    float* __restrict__ scores) {
    __shared__ _Float16 As[2][2][128 * 64];   // 64 KB
    __shared__ _Float16 Bs[2][2][128 * 64];   // 64 KB

    // grid 1024 = 256 bm x 4 bn; XCD chunk swizzle (bijective 8 x 128)
    const int nb = ((blockIdx.x & 7) << 7) | (blockIdx.x >> 3);
    const int bm = nb >> 2;
    const int bn = nb & 3;
    const int tid = threadIdx.x;
    const int lane = tid & 63;
    const int w = tid >> 6;       // 0..7
    const int wr = w >> 2;        // 0..1: rows wr*128..+127  (= A-half wr)
    const int wc = w & 3;         // 0..3: cols wc*64..+63    (= B-half wc>>1)

    // ---- staging geometry: wave w stages rows [w*16, w*16+16) of a half ----
    const int srow = lane >> 3;                 // 0..7
    const int gsl  = (lane & 7) ^ srow;         // pre-swizzled global 16B slot
    const _Float16* Ab = x16 + (size_t)(bm * 256) * KDIM;
    const _Float16* Bb = Wt  + (size_t)(bn * 256) * KDIM;

#define STAGE_A(buf, h, kt)                                                    \
    { _Pragma("unroll")                                                        \
      for (int i = 0; i < 2; ++i) {                                            \
          const int r = w * 16 + i * 8;                                        \
          GLOAD16(Ab + (size_t)((h) * 128 + r + srow) * KDIM + (kt) * 64 + gsl * 8, \
                  &As[buf][h][r * 64]);                                        \
      } }
#define STAGE_B(buf, h, kt)                                                    \
    { _Pragma("unroll")                                                        \
      for (int i = 0; i < 2; ++i) {                                            \
          const int r = w * 16 + i * 8;                                        \
          GLOAD16(Bb + (size_t)((h) * 128 + r + srow) * KDIM + (kt) * 64 + gsl * 8, \
                  &Bs[buf][h][r * 64]);                                        \
      } }

    // ---- frag read geometry ----
    const int frow = lane & 15;
    const int fhi  = lane >> 4;      // 0..3
    const int fx   = frow & 7;       // row&7 for the read swizzle
    const int bsub = (wc & 1) * 64;  // col offset within B-half

#define LDA4(buf, ks, m0)                                                      \
    { _Pragma("unroll")                                                        \
      for (int m = 0; m < 4; ++m)                                              \
          afr[m] = *(const half8*)&As[buf][wr][((m0 + m) * 16 + frow) * 64 +   \
                                              ((((ks) * 4 + fhi) ^ fx) * 8)]; }
#define LDB4(buf, ks)                                                          \
    { _Pragma("unroll")                                                        \
      for (int n = 0; n < 4; ++n)                                              \
          bfr[n] = *(const half8*)&Bs[buf][wc >> 1][(bsub + n * 16 + frow) * 64 + \
                                                    ((((ks) * 4 + fhi) ^ fx) * 8)]; }
#define MFMA16(m0)                                                             \
    { __builtin_amdgcn_s_setprio(1);                                           \
      _Pragma("unroll")                                                        \
      for (int m = 0; m < 4; ++m)                                              \
          _Pragma("unroll")                                                    \
          for (int n = 0; n < 4; ++n)                                          \
              acc[m0 + m][n] = __builtin_amdgcn_mfma_f32_16x16x32_f16(         \
                  afr[m], bfr[n], acc[m0 + m][n], 0, 0, 0);                    \
      __builtin_amdgcn_s_setprio(0); }

#define BAR() __builtin_amdgcn_s_barrier()

    // GROUP(cur, kt1, STG, W0): compute tile in buf 'cur' (4 phases);
    // stage tile kt1 into buf cur^1 (one half-tile per phase) if STG.
#define GROUP(cur, kt1, STG, W0)                                               \
    {                                                                          \
        /* ph0: validate this tile, then ks0 m0-3 */                           \
        if (STG) STAGE_A(cur ^ 1, 0, kt1);                                     \
        asm volatile(W0 ::: "memory");                                         \
        __builtin_amdgcn_sched_barrier(0);                                     \
        BAR();                          /* tile 'cur' visible block-wide */    \
        LDA4(cur, 0, 0); LDB4(cur, 0);                                         \
        MFMA16(0);                                                             \
        BAR();                                                                 \
        /* ph1: ks0 m4-7 */                                                    \
        if (STG) STAGE_A(cur ^ 1, 1, kt1);                                     \
        LDA4(cur, 0, 4);                                                       \
        BAR();                                                                 \
        MFMA16(4);                                                             \
        BAR();                                                                 \
        /* ph2: ks1 m0-3 */                                                    \
        if (STG) STAGE_B(cur ^ 1, 0, kt1);                                     \
        LDA4(cur, 1, 0); LDB4(cur, 1);                                         \
        BAR();                                                                 \
        MFMA16(0);                                                             \
        BAR();                                                                 \
        /* ph3: ks1 m4-7 */                                                    \
        if (STG) STAGE_B(cur ^ 1, 1, kt1);                                     \
        LDA4(cur, 1, 4);                                                       \
        BAR();                                                                 \
        MFMA16(4);                                                             \
        BAR();                                                                 \
    }

    floatx4 acc[8][4] = {};
    half8 afr[4], bfr[4];

    // prologue: stage tile 0 fully (8 loads/wave in flight)
    STAGE_A(0, 0, 0); STAGE_A(0, 1, 0); STAGE_B(0, 0, 0); STAGE_B(0, 1, 0);

    // tiles 0..14: compute + stage next.  ph0 waits own oldest 8 (this tile),
    // keeping the 2 just-issued in flight.  Tile 15: drain.
    for (int kt2 = 0; kt2 < 7; ++kt2) {
        GROUP(0, 2 * kt2 + 1, 1, "s_waitcnt vmcnt(2)");
        GROUP(1, 2 * kt2 + 2, 1, "s_waitcnt vmcnt(2)");
    }
    GROUP(0, 15, 1, "s_waitcnt vmcnt(2)");
    GROUP(1, 0, 0, "s_waitcnt vmcnt(0)");

#undef GROUP
#undef BAR
#undef MFMA16
#undef LDB4
#undef LDA4
#undef STAGE_B
#undef STAGE_A

    // ---- epilogue: fast tanh + ctx dot + 16-lane reduce + atomic ----
    float bv[4], cv[4];
    #pragma unroll
    for (int n = 0; n < 4; ++n) {
        const int col = bn * 256 + wc * 64 + n * 16 + frow;
        bv[n] = bias[col];
        cv[n] = ctx[col];
    }
    #pragma unroll
    for (int m = 0; m < 8; ++m) {
        #pragma unroll
        for (int j = 0; j < 4; ++j) {
            float partial = 0.0f;
            #pragma unroll
            for (int n = 0; n < 4; ++n) {
                const float v = acc[m][n][j] + bv[n];
                const float e = __expf(2.0f * v);          // tanh(v)=1-2/(e^{2v}+1)
                const float t = 1.0f - 2.0f * __builtin_amdgcn_rcpf(e + 1.0f);
                partial += t * cv[n];
            }
            #pragma unroll
            for (int off = 1; off < 16; off <<= 1)
                partial += __shfl_xor(partial, off, 64);
            if (frow == 0) {
                const int rowg = bm * 256 + wr * 128 + m * 16 + fhi * 4 + j;
                atomicAdd(&scores[rowg], partial);
            }
        }
    }
}

// ---------------------------------------------------------------------------
// Fallback GEMM (ws too small): reg-staged fp32 path.
// ---------------------------------------------------------------------------
__global__ __launch_bounds__(256) void score_gemm_f32(
    const float* __restrict__ A32p, const _Float16* __restrict__ Wt,
    const float* __restrict__ bias, const float* __restrict__ ctx,
    float* __restrict__ scores) {
    __shared__ _Float16 As[128 * 64];
    __shared__ _Float16 Bs[128 * 64];

    const int bid = blockIdx.x;
    const int bm = bid >> 3;
    const int bn = bid & 7;
    const int tid = threadIdx.x;
    const int lane = tid & 63;
    const int wid = tid >> 6;
    const int wm = wid >> 1;
    const int wn = wid & 1;

    const int c = tid & 7;
    const int r0 = tid >> 3;
    const int swz = (r0 & 7) << 3;
    const int wcol = (c * 8) ^ swz;

    float4 aF[4][2];
    int4   bR[4];

    #pragma unroll
    for (int i = 0; i < 4; ++i) {
        const int row = r0 + 32 * i;
        const float* p = A32p + (size_t)(bm * 128 + row) * KDIM + c * 8;
        aF[i][0] = *(const float4*)p;
        aF[i][1] = *(const float4*)(p + 4);
        bR[i] = *(const int4*)(Wt + (size_t)(bn * 128 + row) * KDIM + c * 8);
    }

    floatx4 acc[4][4] = {};

    for (int kt = 0; kt < KDIM / 64; ++kt) {
        __syncthreads();
        #pragma unroll
        for (int i = 0; i < 4; ++i) {
            const int row = r0 + 32 * i;
            half8 h;
            h[0] = (_Float16)aF[i][0].x; h[1] = (_Float16)aF[i][0].y;
            h[2] = (_Float16)aF[i][0].z; h[3] = (_Float16)aF[i][0].w;
            h[4] = (_Float16)aF[i][1].x; h[5] = (_Float16)aF[i][1].y;
            h[6] = (_Float16)aF[i][1].z; h[7] = (_Float16)aF[i][1].w;
            *(half8*)&As[row * 64 + wcol] = h;
            *(int4*)&Bs[row * 64 + wcol] = bR[i];
        }
        __syncthreads();

        if (kt + 1 < KDIM / 64) {
            #pragma unroll
            for (int i = 0; i < 4; ++i) {
                const int row = r0 + 32 * i;
                const float* p = A32p + (size_t)(bm * 128 + row) * KDIM + (kt + 1) * 64 + c * 8;
                aF[i][0] = *(const float4*)p;
                aF[i][1] = *(const float4*)(p + 4);
                bR[i] = *(const int4*)(Wt + (size_t)(bn * 128 + row) * KDIM + (kt + 1) * 64 + c * 8);
            }
        }

        #pragma unroll
        for (int s = 0; s < 2; ++s) {
            half8 afr[4], bfr[4];
            const int colr = s * 32 + (lane >> 4) * 8;
            #pragma unroll
            for (int m = 0; m < 4; ++m) {
                const int row = wm * 64 + m * 16 + (lane & 15);
                afr[m] = *(const half8*)&As[row * 64 + (colr ^ ((row & 7) << 3))];
            }
            #pragma unroll
            for (int n = 0; n < 4; ++n) {
                const int row = wn * 64 + n * 16 + (lane & 15);
                bfr[n] = *(const half8*)&Bs[row * 64 + (colr ^ ((row & 7) << 3))];
            }
            #pragma unroll
            for (int m = 0; m < 4; ++m)
                #pragma unroll
                for (int n = 0; n < 4; ++n)
                    acc[m][n] = __builtin_amdgcn_mfma_f32_16x16x32_f16(
                        afr[m], bfr[n], acc[m][n], 0, 0, 0);
        }
    }

    float bv[4], cv[4];
    #pragma unroll
    for (int n = 0; n < 4; ++n) {
        const int col = bn * 128 + wn * 64 + n * 16 + (lane & 15);
        bv[n] = bias[col];
        cv[n] = ctx[col];
    }
    #pragma unroll
    for (int m = 0; m < 4; ++m) {
        #pragma unroll
        for (int j = 0; j < 4; ++j) {
            float partial = 0.0f;
            #pragma unroll
            for (int n = 0; n < 4; ++n) {
                const float v = acc[m][n][j] + bv[n];
                const float e = __expf(2.0f * v);
                const float t = 1.0f - 2.0f * __builtin_amdgcn_rcpf(e + 1.0f);
                partial += t * cv[n];
            }
            #pragma unroll
            for (int off = 1; off < 16; off <<= 1)
                partial += __shfl_xor(partial, off, 64);
            if ((lane & 15) == 0) {
                const int rowg = bm * 128 + wm * 64 + m * 16 + (lane >> 4) * 4 + j;
                atomicAdd(&scores[rowg], partial);
            }
        }
    }
}

// ---------------------------------------------------------------------------
// Kernel 4: softmax over seq dim per batch. 32 blocks x 256 threads.
// ---------------------------------------------------------------------------
__global__ void softmax_kernel(const float* __restrict__ scores,
                               float* __restrict__ weights) {
    const int bb = blockIdx.x;
    const int tid = threadIdx.x;
    const float* s = scores + (size_t)bb * SEQ;
    float* w = weights + (size_t)bb * SEQ;

    __shared__ float red[8];

    float v[8];
    float mx = -1e30f;
    #pragma unroll
    for (int i = 0; i < 8; ++i) {
        v[i] = s[tid + i * 256];
        mx = fmaxf(mx, v[i]);
    }
    #pragma unroll
    for (int off = 1; off < 64; off <<= 1)
        mx = fmaxf(mx, __shfl_xor(mx, off, 64));
    const int wv = tid >> 6;
    if ((tid & 63) == 0) red[wv] = mx;
    __syncthreads();
    mx = fmaxf(fmaxf(red[0], red[1]), fmaxf(red[2], red[3]));

    float sum = 0.0f;
    #pragma unroll
    for (int i = 0; i < 8; ++i) {
        v[i] = __expf(v[i] - mx);
        sum += v[i];
    }
    #pragma unroll
    for (int off = 1; off < 64; off <<= 1)
        sum += __shfl_xor(sum, off, 64);
    if ((tid & 63) == 0) red[4 + wv] = sum;
    __syncthreads();
    sum = red[4] + red[5] + red[6] + red[7];
    const float inv = 1.0f / sum;
    #pragma unroll
    for (int i = 0; i < 8; ++i)
        w[tid + i * 256] = v[i] * inv;
}

// ---------------------------------------------------------------------------
// Kernel 5: weighted pooling (fp32 fallback).
// ---------------------------------------------------------------------------
__global__ __launch_bounds__(256) void pool_kernel(const float* __restrict__ x,
                                                   const float* __restrict__ weights,
                                                   float* __restrict__ out) {
    const int bb = blockIdx.x >> 4;
    const int sc = blockIdx.x & 15;
    const int tid = threadIdx.x;

    const float4* xb = (const float4*)(x + (size_t)bb * SEQ * EMBED) +
                       (size_t)(sc * 128) * (EMBED / 4) + tid;
    const float* wb = weights + (size_t)bb * SEQ + sc * 128;

    float ax = 0.f, ay = 0.f, az = 0.f, aw = 0.f;
    #pragma unroll 4
    for (int s = 0; s < 128; ++s) {
        const float wgt = wb[s];
        const float4 xv = xb[(size_t)s * (EMBED / 4)];
        ax += wgt * xv.x; ay += wgt * xv.y; az += wgt * xv.z; aw += wgt * xv.w;
    }
    float* o = out + (size_t)bb * EMBED + tid * 4;
    atomicAdd(o + 0, ax);
    atomicAdd(o + 1, ay);
    atomicAdd(o + 2, az);
    atomicAdd(o + 3, aw);
}

// ---------------------------------------------------------------------------
// Kernel 5b: weighted pooling (fp16 x16) — halves the read bytes.
// ---------------------------------------------------------------------------
__global__ __launch_bounds__(256) void pool16_kernel(const _Float16* __restrict__ x16,
                                                     const float* __restrict__ weights,
                                                     float* __restrict__ out) {
    const int bb = blockIdx.x >> 4;
    const int sc = blockIdx.x & 15;
    const int tid = threadIdx.x;

    const _Float16* xb = x16 + (size_t)bb * SEQ * EMBED +
                         (size_t)(sc * 128) * EMBED + tid * 4;
    const float* wb = weights + (size_t)bb * SEQ + sc * 128;

    float ax = 0.f, ay = 0.f, az = 0.f, aw = 0.f;
    #pragma unroll 4
    for (int s = 0; s < 128; ++s) {
        const float wgt = wb[s];
        const half4 h = *(const half4*)(xb + (size_t)s * EMBED);
        ax += wgt * (float)h[0]; ay += wgt * (float)h[1];
        az += wgt * (float)h[2]; aw += wgt * (float)h[3];
    }
    float* o = out + (size_t)bb * EMBED + tid * 4;
    atomicAdd(o + 0, ax);
    atomicAdd(o + 1, ay);
    atomicAdd(o + 2, az);
    atomicAdd(o + 3, aw);
}

// ---------------------------------------------------------------------------
extern "C" void kernel_launch(void* const* d_in, const int* in_sizes, int n_in,
                              void* d_out, int out_size, void* d_ws, size_t ws_size,
                              hipStream_t stream) {
    const float* x   = (const float*)d_in[0];
    const float* W   = (const float*)d_in[1];
    const float* b   = (const float*)d_in[2];
    const float* ctx = (const float*)d_in[3];
    float* out = (float*)d_out;

    char* ws = (char*)d_ws;
    _Float16* Wt      = (_Float16*)ws;                               // 2 MB
    float*    scores  = (float*)(ws + (2u << 20));                   // 256 KB
    float*    weights = (float*)(ws + (2u << 20) + (256u << 10));    // 256 KB
    _Float16* x16     = (_Float16*)(ws + (4u << 20));                // 128 MB

    const size_t need = (4ull << 20) + ((size_t)M_TOT * KDIM * 2);
    const bool fast = ws_size >= need;

    hipLaunchKernelGGL(zero_kernel, dim3(M_TOT / 256), dim3(256), 0, stream, scores, out);
    hipLaunchKernelGGL(transpose_w_kernel, dim3(32, 32), dim3(32, 8), 0, stream, W, Wt);

    if (fast) {
        hipLaunchKernelGGL(cvt_x_kernel, dim3(4096), dim3(256), 0, stream, x, x16);
        hipLaunchKernelGGL(score_gemm13, dim3(1024), dim3(512), 0, stream,
                           x16, Wt, b, ctx, scores);
    } else {
        hipLaunchKernelGGL(score_gemm_f32, dim3(4096), dim3(256), 0, stream,
                           x, Wt, b, ctx, scores);
    }

    hipLaunchKernelGGL(softmax_kernel, dim3(BATCH), dim3(256), 0, stream, scores, weights);

    if (fast) {
        hipLaunchKernelGGL(pool16_kernel, dim3(BATCH * 16), dim3(256), 0, stream,
                           x16, weights, out);
    } else {
        hipLaunchKernelGGL(pool_kernel, dim3(BATCH * 16), dim3(256), 0, stream,
                           x, weights, out);
    }
}

// Round 16
// 283.823 us; speedup vs baseline: 1.0822x; 1.0822x over previous
//
#include <hip/hip_runtime.h>
#include <hip/hip_bf16.h>

typedef _Float16 half8 __attribute__((ext_vector_type(8)));
typedef _Float16 half4 __attribute__((ext_vector_type(4)));
typedef float floatx4 __attribute__((ext_vector_type(4)));

#define EMBED 1024
#define SEQ   2048
#define BATCH 32
#define M_TOT (BATCH * SEQ)   // 65536 rows
#define KDIM  1024
#define NDIM  1024

// async global->LDS, 16B per lane, dest = wave-uniform base + lane*16
#define GLOAD16(g, l) __builtin_amdgcn_global_load_lds(                      \
    (const __attribute__((address_space(1))) void*)(g),                      \
    (__attribute__((address_space(3))) void*)(l), 16, 0, 0)

// ---------------------------------------------------------------------------
// Kernel 1: transpose + convert W[K][N] fp32 -> Wt[N][K] fp16
// ---------------------------------------------------------------------------
__global__ void transpose_w_kernel(const float* __restrict__ W,
                                   _Float16* __restrict__ Wt) {
    __shared__ float t[32][33];
    const int kt = blockIdx.x * 32;
    const int nt = blockIdx.y * 32;
    #pragma unroll
    for (int i = 0; i < 4; ++i)
        t[threadIdx.y + 8 * i][threadIdx.x] =
            W[(size_t)(kt + threadIdx.y + 8 * i) * NDIM + nt + threadIdx.x];
    __syncthreads();
    #pragma unroll
    for (int i = 0; i < 4; ++i)
        Wt[(size_t)(nt + threadIdx.y + 8 * i) * KDIM + kt + threadIdx.x] =
            (_Float16)t[threadIdx.x][threadIdx.y + 8 * i];
}

// ---------------------------------------------------------------------------
// Kernel 2: zero scores + out
// ---------------------------------------------------------------------------
__global__ void zero_kernel(float* __restrict__ scores, float* __restrict__ out) {
    const int i = blockIdx.x * 256 + threadIdx.x;
    if (i < M_TOT) scores[i] = 0.0f;
    if (i < BATCH * EMBED) out[i] = 0.0f;
}

// ---------------------------------------------------------------------------
// Kernel 2b: convert x fp32 -> fp16 (64M elements)
// ---------------------------------------------------------------------------
__global__ __launch_bounds__(256) void cvt_x_kernel(const float* __restrict__ x,
                                                    _Float16* __restrict__ x16) {
    const size_t stride = (size_t)gridDim.x * 256 * 8;
    for (size_t i = ((size_t)blockIdx.x * 256 + threadIdx.x) * 8;
         i < (size_t)M_TOT * KDIM; i += stride) {
        const float4 a = *(const float4*)(x + i);
        const float4 b = *(const float4*)(x + i + 4);
        half8 h;
        h[0] = (_Float16)a.x; h[1] = (_Float16)a.y; h[2] = (_Float16)a.z; h[3] = (_Float16)a.w;
        h[4] = (_Float16)b.x; h[5] = (_Float16)b.y; h[6] = (_Float16)b.z; h[7] = (_Float16)b.w;
        *(half8*)(x16 + i) = h;
    }
}

// ---------------------------------------------------------------------------
// Kernel 3: fused scores GEMM — r11's loop, BM DOUBLED to cut vmem bytes/output.
// BM=256, BN=128, BK=32, 512 threads = 8 waves (4M x 2N), wave tile 64x64
// (identical per-wave code to r11), mfma_f32_16x16x32_f16.
// Theory: all prior structures plateau because the per-CU L1/vector-memory
// path carries 24 KB per 128x128-output K-step (12 MB/CU total).  This tile
// carries 24 KB per 256x128 output -> HALF the bytes per output (6 MB/CU):
//   A: 16 KB/K-step via gload_lds (2 instr/wave), B: 8 KB via gload_lds
//   (1 instr/wave) — B read by both wn-waves from LDS (no duplication).
// Counted vmcnt(3) (3 loads/wave/tile in flight), raw barriers, verified
// conflict-free swizzle for 64B rows: phys = s ^ ((row>>1)&3), staged via
// pre-swizzled global slot g = (l&3)^((l>>3)&3)  [r10: conflicts == 0].
// LDS 48 KB -> ~3 blocks/CU.
// ---------------------------------------------------------------------------
__global__ __launch_bounds__(512, 4) void score_gemm14(
    const _Float16* __restrict__ x16, const _Float16* __restrict__ Wt,
    const float* __restrict__ bias, const float* __restrict__ ctx,
    float* __restrict__ scores) {
    __shared__ _Float16 As[2][256 * 32];   // 16 KB per buf
    __shared__ _Float16 Bs[2][128 * 32];   // 8 KB per buf

    // grid 2048 = 256 bm x 8 bn; XCD chunk swizzle (bijective 8 x 256)
    const int nb = ((blockIdx.x & 7) << 8) | (blockIdx.x >> 3);
    const int bm = nb >> 3;       // 0..255, contiguous per XCD
    const int bn = nb & 7;        // 0..7, innermost (A-panel L2/L3 reuse)
    const int tid = threadIdx.x;
    const int lane = tid & 63;
    const int w = tid >> 6;       // 0..7
    const int wm = w >> 1;        // 0..3 (64-row group)
    const int wn = w & 1;         // 0..1 (64-col group)

    // staging: instr j covers rows j*16..j*16+15 (1 KB).  A: 16 instrs,
    // wave w owns {w, w+8}.  B: 8 instrs, wave w owns {w}.
    // lane l -> row j*16 + (l>>2), LDS slot l&3 linear; global 16B slot
    // pre-swizzled g = (l&3) ^ ((l>>3)&3)  [= (row>>1)&3].
    const int lrow = lane >> 2;                     // 0..15
    const int gslot = (lane & 3) ^ ((lane >> 3) & 3);
    const int gcol = gslot * 8;                     // halves

    const _Float16* Ab = x16 + (size_t)(bm * 256) * KDIM;
    const _Float16* Bb = Wt  + (size_t)(bn * 128) * KDIM;

    floatx4 acc[4][4] = {};

    // frag read: row = base + frow, logical slot s = lane>>4,
    // physical p = s ^ ((frow>>1)&3)   [0 conflicts measured, r10/r11]
    const int frow = lane & 15;
    const int fslot = ((lane >> 4) ^ ((frow >> 1) & 3)) * 8;   // halves

    #define STAGE(buf, kt)                                                        \
        {                                                                         \
            const int kc = (kt) * 32 + gcol;                                      \
            _Pragma("unroll")                                                     \
            for (int i = 0; i < 2; ++i) {                                         \
                const int j = w + i * 8;                                          \
                GLOAD16(Ab + (size_t)(j * 16 + lrow) * KDIM + kc, &As[buf][j * 512]); \
            }                                                                     \
            GLOAD16(Bb + (size_t)(w * 16 + lrow) * KDIM + kc, &Bs[buf][w * 512]); \
        }

    #define COMPUTE(buf)                                                          \
        {                                                                         \
            half8 afr[4], bfr[4];                                                 \
            _Pragma("unroll")                                                     \
            for (int m = 0; m < 4; ++m)                                           \
                afr[m] = *(const half8*)&As[buf][(wm * 64 + m * 16 + frow) * 32 + fslot]; \
            _Pragma("unroll")                                                     \
            for (int n = 0; n < 4; ++n)                                           \
                bfr[n] = *(const half8*)&Bs[buf][(wn * 64 + n * 16 + frow) * 32 + fslot]; \
            _Pragma("unroll")                                                     \
            for (int m = 0; m < 4; ++m)                                           \
                _Pragma("unroll")                                                 \
                for (int n = 0; n < 4; ++n)                                       \
                    acc[m][n] = __builtin_amdgcn_mfma_f32_16x16x32_f16(           \
                        afr[m], bfr[n], acc[m][n], 0, 0, 0);                      \
        }

    STAGE(0, 0);               // 3 loads/wave in flight (tile 0)

    for (int kt = 0; kt < 31; ++kt) {
        const int cur = kt & 1;
        STAGE(cur ^ 1, kt + 1);                 // +3 -> 6 in flight
        asm volatile("s_waitcnt vmcnt(3)" ::: "memory");  // tile kt done; kt+1 stays
        __builtin_amdgcn_sched_barrier(0);
        __builtin_amdgcn_s_barrier();           // block-wide: tile kt ready
        COMPUTE(cur);
        __builtin_amdgcn_s_barrier();           // reads done; buf reusable
    }
    // kt = 31 (cur = 1): drain the last 3
    asm volatile("s_waitcnt vmcnt(0)" ::: "memory");
    __builtin_amdgcn_sched_barrier(0);
    __builtin_amdgcn_s_barrier();
    COMPUTE(1);

    #undef COMPUTE
    #undef STAGE

    // ---- epilogue: fast tanh + ctx dot + 16-lane reduce + atomic ----
    float bv[4], cv[4];
    #pragma unroll
    for (int n = 0; n < 4; ++n) {
        const int col = bn * 128 + wn * 64 + n * 16 + frow;
        bv[n] = bias[col];
        cv[n] = ctx[col];
    }
    #pragma unroll
    for (int m = 0; m < 4; ++m) {
        #pragma unroll
        for (int j = 0; j < 4; ++j) {
            float partial = 0.0f;
            #pragma unroll
            for (int n = 0; n < 4; ++n) {
                const float v = acc[m][n][j] + bv[n];
                const float e = __expf(2.0f * v);          // tanh(v)=1-2/(e^{2v}+1)
                const float t = 1.0f - 2.0f * __builtin_amdgcn_rcpf(e + 1.0f);
                partial += t * cv[n];
            }
            #pragma unroll
            for (int off = 1; off < 16; off <<= 1)
                partial += __shfl_xor(partial, off, 64);
            if (frow == 0) {
                const int rowg = bm * 256 + wm * 64 + m * 16 + (lane >> 4) * 4 + j;
                atomicAdd(&scores[rowg], partial);
            }
        }
    }
}

// ---------------------------------------------------------------------------
// Fallback GEMM (ws too small): reg-staged fp32 path.
// ---------------------------------------------------------------------------
__global__ __launch_bounds__(256) void score_gemm_f32(
    const float* __restrict__ A32p, const _Float16* __restrict__ Wt,
    const float* __restrict__ bias, const float* __restrict__ ctx,
    float* __restrict__ scores) {
    __shared__ _Float16 As[128 * 64];
    __shared__ _Float16 Bs[128 * 64];

    const int bid = blockIdx.x;
    const int bm = bid >> 3;
    const int bn = bid & 7;
    const int tid = threadIdx.x;
    const int lane = tid & 63;
    const int wid = tid >> 6;
    const int wm = wid >> 1;
    const int wn = wid & 1;

    const int c = tid & 7;
    const int r0 = tid >> 3;
    const int swz = (r0 & 7) << 3;
    const int wcol = (c * 8) ^ swz;

    float4 aF[4][2];
    int4   bR[4];

    #pragma unroll
    for (int i = 0; i < 4; ++i) {
        const int row = r0 + 32 * i;
        const float* p = A32p + (size_t)(bm * 128 + row) * KDIM + c * 8;
        aF[i][0] = *(const float4*)p;
        aF[i][1] = *(const float4*)(p + 4);
        bR[i] = *(const int4*)(Wt + (size_t)(bn * 128 + row) * KDIM + c * 8);
    }

    floatx4 acc[4][4] = {};

    for (int kt = 0; kt < KDIM / 64; ++kt) {
        __syncthreads();
        #pragma unroll
        for (int i = 0; i < 4; ++i) {
            const int row = r0 + 32 * i;
            half8 h;
            h[0] = (_Float16)aF[i][0].x; h[1] = (_Float16)aF[i][0].y;
            h[2] = (_Float16)aF[i][0].z; h[3] = (_Float16)aF[i][0].w;
            h[4] = (_Float16)aF[i][1].x; h[5] = (_Float16)aF[i][1].y;
            h[6] = (_Float16)aF[i][1].z; h[7] = (_Float16)aF[i][1].w;
            *(half8*)&As[row * 64 + wcol] = h;
            *(int4*)&Bs[row * 64 + wcol] = bR[i];
        }
        __syncthreads();

        if (kt + 1 < KDIM / 64) {
            #pragma unroll
            for (int i = 0; i < 4; ++i) {
                const int row = r0 + 32 * i;
                const float* p = A32p + (size_t)(bm * 128 + row) * KDIM + (kt + 1) * 64 + c * 8;
                aF[i][0] = *(const float4*)p;
                aF[i][1] = *(const float4*)(p + 4);
                bR[i] = *(const int4*)(Wt + (size_t)(bn * 128 + row) * KDIM + (kt + 1) * 64 + c * 8);
            }
        }

        #pragma unroll
        for (int s = 0; s < 2; ++s) {
            half8 afr[4], bfr[4];
            const int colr = s * 32 + (lane >> 4) * 8;
            #pragma unroll
            for (int m = 0; m < 4; ++m) {
                const int row = wm * 64 + m * 16 + (lane & 15);
                afr[m] = *(const half8*)&As[row * 64 + (colr ^ ((row & 7) << 3))];
            }
            #pragma unroll
            for (int n = 0; n < 4; ++n) {
                const int row = wn * 64 + n * 16 + (lane & 15);
                bfr[n] = *(const half8*)&Bs[row * 64 + (colr ^ ((row & 7) << 3))];
            }
            #pragma unroll
            for (int m = 0; m < 4; ++m)
                #pragma unroll
                for (int n = 0; n < 4; ++n)
                    acc[m][n] = __builtin_amdgcn_mfma_f32_16x16x32_f16(
                        afr[m], bfr[n], acc[m][n], 0, 0, 0);
        }
    }

    float bv[4], cv[4];
    #pragma unroll
    for (int n = 0; n < 4; ++n) {
        const int col = bn * 128 + wn * 64 + n * 16 + (lane & 15);
        bv[n] = bias[col];
        cv[n] = ctx[col];
    }
    #pragma unroll
    for (int m = 0; m < 4; ++m) {
        #pragma unroll
        for (int j = 0; j < 4; ++j) {
            float partial = 0.0f;
            #pragma unroll
            for (int n = 0; n < 4; ++n) {
                const float v = acc[m][n][j] + bv[n];
                const float e = __expf(2.0f * v);
                const float t = 1.0f - 2.0f * __builtin_amdgcn_rcpf(e + 1.0f);
                partial += t * cv[n];
            }
            #pragma unroll
            for (int off = 1; off < 16; off <<= 1)
                partial += __shfl_xor(partial, off, 64);
            if ((lane & 15) == 0) {
                const int rowg = bm * 128 + wm * 64 + m * 16 + (lane >> 4) * 4 + j;
                atomicAdd(&scores[rowg], partial);
            }
        }
    }
}

// ---------------------------------------------------------------------------
// Kernel 4: softmax over seq dim per batch. 32 blocks x 256 threads.
// ---------------------------------------------------------------------------
__global__ void softmax_kernel(const float* __restrict__ scores,
                               float* __restrict__ weights) {
    const int bb = blockIdx.x;
    const int tid = threadIdx.x;
    const float* s = scores + (size_t)bb * SEQ;
    float* w = weights + (size_t)bb * SEQ;

    __shared__ float red[8];

    float v[8];
    float mx = -1e30f;
    #pragma unroll
    for (int i = 0; i < 8; ++i) {
        v[i] = s[tid + i * 256];
        mx = fmaxf(mx, v[i]);
    }
    #pragma unroll
    for (int off = 1; off < 64; off <<= 1)
        mx = fmaxf(mx, __shfl_xor(mx, off, 64));
    const int wv = tid >> 6;
    if ((tid & 63) == 0) red[wv] = mx;
    __syncthreads();
    mx = fmaxf(fmaxf(red[0], red[1]), fmaxf(red[2], red[3]));

    float sum = 0.0f;
    #pragma unroll
    for (int i = 0; i < 8; ++i) {
        v[i] = __expf(v[i] - mx);
        sum += v[i];
    }
    #pragma unroll
    for (int off = 1; off < 64; off <<= 1)
        sum += __shfl_xor(sum, off, 64);
    if ((tid & 63) == 0) red[4 + wv] = sum;
    __syncthreads();
    sum = red[4] + red[5] + red[6] + red[7];
    const float inv = 1.0f / sum;
    #pragma unroll
    for (int i = 0; i < 8; ++i)
        w[tid + i * 256] = v[i] * inv;
}

// ---------------------------------------------------------------------------
// Kernel 5: weighted pooling (fp32 fallback).
// ---------------------------------------------------------------------------
__global__ __launch_bounds__(256) void pool_kernel(const float* __restrict__ x,
                                                   const float* __restrict__ weights,
                                                   float* __restrict__ out) {
    const int bb = blockIdx.x >> 4;
    const int sc = blockIdx.x & 15;
    const int tid = threadIdx.x;

    const float4* xb = (const float4*)(x + (size_t)bb * SEQ * EMBED) +
                       (size_t)(sc * 128) * (EMBED / 4) + tid;
    const float* wb = weights + (size_t)bb * SEQ + sc * 128;

    float ax = 0.f, ay = 0.f, az = 0.f, aw = 0.f;
    #pragma unroll 4
    for (int s = 0; s < 128; ++s) {
        const float wgt = wb[s];
        const float4 xv = xb[(size_t)s * (EMBED / 4)];
        ax += wgt * xv.x; ay += wgt * xv.y; az += wgt * xv.z; aw += wgt * xv.w;
    }
    float* o = out + (size_t)bb * EMBED + tid * 4;
    atomicAdd(o + 0, ax);
    atomicAdd(o + 1, ay);
    atomicAdd(o + 2, az);
    atomicAdd(o + 3, aw);
}

// ---------------------------------------------------------------------------
// Kernel 5b: weighted pooling (fp16 x16) — halves the read bytes.
// ---------------------------------------------------------------------------
__global__ __launch_bounds__(256) void pool16_kernel(const _Float16* __restrict__ x16,
                                                     const float* __restrict__ weights,
                                                     float* __restrict__ out) {
    const int bb = blockIdx.x >> 4;
    const int sc = blockIdx.x & 15;
    const int tid = threadIdx.x;

    const _Float16* xb = x16 + (size_t)bb * SEQ * EMBED +
                         (size_t)(sc * 128) * EMBED + tid * 4;
    const float* wb = weights + (size_t)bb * SEQ + sc * 128;

    float ax = 0.f, ay = 0.f, az = 0.f, aw = 0.f;
    #pragma unroll 4
    for (int s = 0; s < 128; ++s) {
        const float wgt = wb[s];
        const half4 h = *(const half4*)(xb + (size_t)s * EMBED);
        ax += wgt * (float)h[0]; ay += wgt * (float)h[1];
        az += wgt * (float)h[2]; aw += wgt * (float)h[3];
    }
    float* o = out + (size_t)bb * EMBED + tid * 4;
    atomicAdd(o + 0, ax);
    atomicAdd(o + 1, ay);
    atomicAdd(o + 2, az);
    atomicAdd(o + 3, aw);
}

// ---------------------------------------------------------------------------
extern "C" void kernel_launch(void* const* d_in, const int* in_sizes, int n_in,
                              void* d_out, int out_size, void* d_ws, size_t ws_size,
                              hipStream_t stream) {
    const float* x   = (const float*)d_in[0];
    const float* W   = (const float*)d_in[1];
    const float* b   = (const float*)d_in[2];
    const float* ctx = (const float*)d_in[3];
    float* out = (float*)d_out;

    char* ws = (char*)d_ws;
    _Float16* Wt      = (_Float16*)ws;                               // 2 MB
    float*    scores  = (float*)(ws + (2u << 20));                   // 256 KB
    float*    weights = (float*)(ws + (2u << 20) + (256u << 10));    // 256 KB
    _Float16* x16     = (_Float16*)(ws + (4u << 20));                // 128 MB

    const size_t need = (4ull << 20) + ((size_t)M_TOT * KDIM * 2);
    const bool fast = ws_size >= need;

    hipLaunchKernelGGL(zero_kernel, dim3(M_TOT / 256), dim3(256), 0, stream, scores, out);
    hipLaunchKernelGGL(transpose_w_kernel, dim3(32, 32), dim3(32, 8), 0, stream, W, Wt);

    if (fast) {
        hipLaunchKernelGGL(cvt_x_kernel, dim3(4096), dim3(256), 0, stream, x, x16);
        hipLaunchKernelGGL(score_gemm14, dim3(2048), dim3(512), 0, stream,
                           x16, Wt, b, ctx, scores);
    } else {
        hipLaunchKernelGGL(score_gemm_f32, dim3(4096), dim3(256), 0, stream,
                           x, Wt, b, ctx, scores);
    }

    hipLaunchKernelGGL(softmax_kernel, dim3(BATCH), dim3(256), 0, stream, scores, weights);

    if (fast) {
        hipLaunchKernelGGL(pool16_kernel, dim3(BATCH * 16), dim3(256), 0, stream,
                           x16, weights, out);
    } else {
        hipLaunchKernelGGL(pool_kernel, dim3(BATCH * 16), dim3(256), 0, stream,
                           x, weights, out);
    }
}